// Round 2
// baseline (7798.087 us; speedup 1.0000x reference)
//
#include <hip/hip_runtime.h>
#include <hip/hip_fp16.h>
#include <math.h>

// ---------------------------------------------------------------------------
// Branch 1: fused sample (top-40 of 80 cosine sims) + MLP (64->256 relu ->256)
// + L2 normalize. One block per (b, n) pair; 4096 blocks, 256 threads.
// LDS plan (~35 KB -> 4 blocks/CU):
//   region A (22.5 KB): xall[81][65] fp32 gather buffer, later reused as
//                       t1h[44][256] fp16.
//   region B (11.3 KB): xs[44][64] fp32 (winner rows, padded to 44).
// ---------------------------------------------------------------------------
__global__ __launch_bounds__(256, 4) void k_branch1(
    const float* __restrict__ feat1, const int* __restrict__ patch_id1,
    const int* __restrict__ local_id1, const float* __restrict__ W3,
    const float* __restrict__ b3, const float* __restrict__ W4,
    const float* __restrict__ b4, float* __restrict__ out1)
{
    __shared__ __align__(16) char regA[44 * 256 * 2];   // 22528 B
    __shared__ __align__(16) float xs[44 * 64];         // 11264 B
    __shared__ double normd[81];
    __shared__ double sims[80];
    __shared__ int winners[40];

    float* xall = (float*)regA;        // [81][65] fp32 (21060 B <= 22528)
    __half* t1h = (__half*)regA;       // [44][256] fp16

    const int row = blockIdx.x;          // 0..4095
    const int b = row >> 9;
    const int n = row & 511;
    const int tid = threadIdx.x;
    const float* fb = feat1 + (size_t)b * 64 * 16384;   // (C=64, HW=16384)
    const int pid = patch_id1[n];
    const int* lids = local_id1 + n * 80;

    // phase 1: gather 81 rows (80 local + center) into LDS, c-major over idx
    // so consecutive threads hit adjacent pixels at fixed channel (L1/L2 friendly)
    #pragma unroll 4
    for (int idx = tid; idx < 81 * 64; idx += 256) {
        const int c = idx / 81;
        const int l = idx - c * 81;
        const int pix = (l < 80) ? lids[l] : pid;
        xall[l * 65 + c] = fb[(size_t)c * 16384 + pix];
    }
    __syncthreads();

    // phase 2: row norms (fp64) — t-th thread does row t
    if (tid < 81) {
        double q = 0.0;
        #pragma unroll 8
        for (int c = 0; c < 64; ++c) {
            const double v = (double)xall[tid * 65 + c];
            q += v * v;
        }
        double nl = sqrt(q); if (nl < 1e-12) nl = 1e-12;
        normd[tid] = nl;
    }
    __syncthreads();

    // phase 3: cosine sims vs center (row 80)
    if (tid < 80) {
        double d = 0.0;
        #pragma unroll 8
        for (int c = 0; c < 64; ++c)
            d += (double)xall[tid * 65 + c] * (double)xall[80 * 65 + c];
        sims[tid] = d / (normd[tid] * normd[80]);
    }
    __syncthreads();

    // phase 4: stable top-40 via rank (matches jax.lax.top_k tie-break)
    if (tid < 80) {
        const double s = sims[tid];
        int rank = 0;
        for (int j = 0; j < 80; ++j) {
            const double sj = sims[j];
            rank += (sj > s) || (sj == s && j < tid);
        }
        if (rank < 40) winners[rank] = tid;
    }
    __syncthreads();

    // phase 5: build xs (row 0 = center, 1..40 winners, 41..43 pad) from LDS
    for (int m = tid; m < 44 * 64; m += 256) {
        const int mi = m >> 6, c = m & 63;
        const int src = (mi >= 1 && mi <= 40) ? winners[mi - 1] : 80;
        xs[m] = xall[src * 65 + c];
    }
    __syncthreads();   // after this, xall region is dead -> t1h may overwrite

    const int jg = tid & 63;   // column group (4 consecutive cols)
    const int g = tid >> 6;    // mi-group (one wave each)
    const int j0 = jg * 4;
    const int mb = g * 11;

    // ---- stage 1: t1 = relu(xs @ W3^T + b3) -> t1h (fp16) ----
    {
        float acc[11][4];
        #pragma unroll
        for (int r = 0; r < 11; ++r) {
            acc[r][0] = 0.f; acc[r][1] = 0.f; acc[r][2] = 0.f; acc[r][3] = 0.f;
        }
        const float4* W3f = (const float4*)W3;   // row j: W3f[j*16 + c4]
        const float4* xsf = (const float4*)xs;   // row mi: xsf[mi*16 + c4]
        #pragma unroll 4
        for (int c4 = 0; c4 < 16; ++c4) {
            const float4 w0 = W3f[(j0 + 0) * 16 + c4];
            const float4 w1 = W3f[(j0 + 1) * 16 + c4];
            const float4 w2 = W3f[(j0 + 2) * 16 + c4];
            const float4 w3 = W3f[(j0 + 3) * 16 + c4];
            #pragma unroll
            for (int r = 0; r < 11; ++r) {
                const float4 x4 = xsf[(mb + r) * 16 + c4];  // LDS broadcast
                acc[r][0] += x4.x*w0.x + x4.y*w0.y + x4.z*w0.z + x4.w*w0.w;
                acc[r][1] += x4.x*w1.x + x4.y*w1.y + x4.z*w1.z + x4.w*w1.w;
                acc[r][2] += x4.x*w2.x + x4.y*w2.y + x4.z*w2.z + x4.w*w2.w;
                acc[r][3] += x4.x*w3.x + x4.y*w3.y + x4.z*w3.z + x4.w*w3.w;
            }
        }
        const float bb0 = b3[j0], bb1 = b3[j0+1], bb2 = b3[j0+2], bb3 = b3[j0+3];
        #pragma unroll
        for (int r = 0; r < 11; ++r) {
            const float v0 = fmaxf(acc[r][0] + bb0, 0.f);
            const float v1 = fmaxf(acc[r][1] + bb1, 0.f);
            const float v2 = fmaxf(acc[r][2] + bb2, 0.f);
            const float v3 = fmaxf(acc[r][3] + bb3, 0.f);
            union { __half2 h2[2]; float2 f2; } u;
            u.h2[0] = __floats2half2_rn(v0, v1);
            u.h2[1] = __floats2half2_rn(v2, v3);
            *(float2*)&t1h[(mb + r) * 256 + j0] = u.f2;   // 8B store
        }
    }
    __syncthreads();

    // ---- stage 2: y = t1 @ W4^T + b4, L2-normalize, store ----
    {
        float acc[11][4];
        #pragma unroll
        for (int r = 0; r < 11; ++r) {
            acc[r][0] = 0.f; acc[r][1] = 0.f; acc[r][2] = 0.f; acc[r][3] = 0.f;
        }
        const float4* W4f = (const float4*)W4;    // row j: W4f[j*64 + k4]
        const float4* t1f = (const float4*)t1h;   // row mi: t1f[mi*32 + j8] (8 halves)
        #pragma unroll 2
        for (int j8 = 0; j8 < 32; ++j8) {
            const float4 w00 = W4f[(j0 + 0) * 64 + j8 * 2 + 0];
            const float4 w01 = W4f[(j0 + 0) * 64 + j8 * 2 + 1];
            const float4 w10 = W4f[(j0 + 1) * 64 + j8 * 2 + 0];
            const float4 w11 = W4f[(j0 + 1) * 64 + j8 * 2 + 1];
            const float4 w20 = W4f[(j0 + 2) * 64 + j8 * 2 + 0];
            const float4 w21 = W4f[(j0 + 2) * 64 + j8 * 2 + 1];
            const float4 w30 = W4f[(j0 + 3) * 64 + j8 * 2 + 0];
            const float4 w31 = W4f[(j0 + 3) * 64 + j8 * 2 + 1];
            #pragma unroll
            for (int r = 0; r < 11; ++r) {
                const float4 tv = t1f[(mb + r) * 32 + j8];  // LDS broadcast, 8 halves
                const __half2* hp = (const __half2*)&tv;
                const float2 a0 = __half22float2(hp[0]);
                const float2 a1 = __half22float2(hp[1]);
                const float2 a2 = __half22float2(hp[2]);
                const float2 a3 = __half22float2(hp[3]);
                acc[r][0] += a0.x*w00.x + a0.y*w00.y + a1.x*w00.z + a1.y*w00.w
                           + a2.x*w01.x + a2.y*w01.y + a3.x*w01.z + a3.y*w01.w;
                acc[r][1] += a0.x*w10.x + a0.y*w10.y + a1.x*w10.z + a1.y*w10.w
                           + a2.x*w11.x + a2.y*w11.y + a3.x*w11.z + a3.y*w11.w;
                acc[r][2] += a0.x*w20.x + a0.y*w20.y + a1.x*w20.z + a1.y*w20.w
                           + a2.x*w21.x + a2.y*w21.y + a3.x*w21.z + a3.y*w21.w;
                acc[r][3] += a0.x*w30.x + a0.y*w30.y + a1.x*w30.z + a1.y*w30.w
                           + a2.x*w31.x + a2.y*w31.y + a3.x*w31.z + a3.y*w31.w;
            }
        }
        const float bb0 = b4[j0], bb1 = b4[j0+1], bb2 = b4[j0+2], bb3 = b4[j0+3];
        #pragma unroll
        for (int r = 0; r < 11; ++r) {
            const float y0 = acc[r][0] + bb0;
            const float y1 = acc[r][1] + bb1;
            const float y2 = acc[r][2] + bb2;
            const float y3 = acc[r][3] + bb3;
            float p = y0*y0 + y1*y1 + y2*y2 + y3*y3;
            for (int o = 1; o < 64; o <<= 1) p += __shfl_xor(p, o);
            const float inv = 1.f / (sqrtf(p) + 1e-7f);
            const int mi = mb + r;
            if (mi < 41) {
                float4 o4 = make_float4(y0*inv, y1*inv, y2*inv, y3*inv);
                *(float4*)&out1[((size_t)row * 41 + mi) * 256 + j0] = o4;
            }
        }
    }
}

// ---------------------------------------------------------------------------
// Branch 0, kernel A: sample + mean + GEMM1 (512x1024x512). One block per row.
// ---------------------------------------------------------------------------
__global__ __launch_bounds__(256) void k_b0_front(
    const float* __restrict__ feat0, const int* __restrict__ patch_id0,
    const int* __restrict__ local_id0, const float* __restrict__ W1,
    const float* __restrict__ b1, float* __restrict__ h)
{
    __shared__ __align__(16) float loc[9][512];   // rows 0..7 local, 8 = center
    __shared__ __align__(16) float xm[512];
    __shared__ double normd[9];
    __shared__ double sims[8];
    __shared__ int winners[4];

    const int row = blockIdx.x;          // 0..511
    const int b = row >> 6;
    const int n = row & 63;
    const int tid = threadIdx.x;
    const int lane = tid & 63;
    const int w = tid >> 6;
    const float* fb = feat0 + (size_t)b * 512 * 64;   // (C=512, HW=64)
    const int pid = patch_id0[n];

    for (int idx = tid; idx < 9 * 512; idx += 256) {
        const int l = idx >> 9, c = idx & 511;
        const int pix = (l < 8) ? local_id0[n * 8 + l] : pid;
        loc[l][c] = fb[(size_t)c * 64 + pix];
    }
    __syncthreads();

    // norms (fp64), wave w handles rows w, w+4, ...
    for (int l = w; l < 9; l += 4) {
        double q = 0.0;
        for (int c = lane; c < 512; c += 64) {
            const double v = (double)loc[l][c];
            q += v * v;
        }
        for (int o = 32; o > 0; o >>= 1) q += __shfl_down(q, o);
        if (lane == 0) {
            double nl = sqrt(q); if (nl < 1e-12) nl = 1e-12;
            normd[l] = nl;
        }
    }
    __syncthreads();

    for (int l = w; l < 8; l += 4) {
        double d = 0.0;
        for (int c = lane; c < 512; c += 64)
            d += (double)loc[l][c] * (double)loc[8][c];
        for (int o = 32; o > 0; o >>= 1) d += __shfl_down(d, o);
        if (lane == 0) sims[l] = d / (normd[l] * normd[8]);
    }
    __syncthreads();

    if (tid < 8) {
        const double s = sims[tid];
        int rank = 0;
        for (int j = 0; j < 8; ++j) {
            const double sj = sims[j];
            rank += (sj > s) || (sj == s && j < tid);
        }
        if (rank < 4) winners[rank] = tid;
    }
    __syncthreads();

    for (int c = tid; c < 512; c += 256) {
        float a = loc[8][c];
        for (int r = 0; r < 4; ++r) a += loc[winners[r]][c];
        xm[c] = a * 0.2f;
    }
    __syncthreads();

    // GEMM1: thread computes cols j0..j0+3 of h row
    {
        const int j0 = tid * 4;
        float a0 = 0.f, a1 = 0.f, a2 = 0.f, a3 = 0.f;
        const float4* W1f = (const float4*)W1;   // row j: W1f[j*128 + k]
        const float4* xf = (const float4*)xm;
        #pragma unroll 4
        for (int k = 0; k < 128; ++k) {
            const float4 x4 = xf[k];
            const float4 w0 = W1f[(j0 + 0) * 128 + k];
            const float4 w1 = W1f[(j0 + 1) * 128 + k];
            const float4 w2 = W1f[(j0 + 2) * 128 + k];
            const float4 w3 = W1f[(j0 + 3) * 128 + k];
            a0 += x4.x*w0.x + x4.y*w0.y + x4.z*w0.z + x4.w*w0.w;
            a1 += x4.x*w1.x + x4.y*w1.y + x4.z*w1.z + x4.w*w1.w;
            a2 += x4.x*w2.x + x4.y*w2.y + x4.z*w2.z + x4.w*w2.w;
            a3 += x4.x*w3.x + x4.y*w3.y + x4.z*w3.z + x4.w*w3.w;
        }
        float4 o4 = make_float4(a0 + b1[j0], a1 + b1[j0+1], a2 + b1[j0+2], a3 + b1[j0+3]);
        *(float4*)&h[(size_t)row * 1024 + j0] = o4;
    }
}

__global__ __launch_bounds__(64) void k_bnstats(
    const float* __restrict__ h, float* __restrict__ mu, float* __restrict__ rstd)
{
    const int j = blockIdx.x;   // 0..1023
    const int t = threadIdx.x;  // 64
    float s = 0.f, ss = 0.f;
    for (int i = t; i < 512; i += 64) {
        const float v = h[(size_t)i * 1024 + j];
        s += v; ss += v * v;
    }
    for (int o = 32; o > 0; o >>= 1) { s += __shfl_down(s, o); ss += __shfl_down(ss, o); }
    if (t == 0) {
        const float m = s * (1.f / 512.f);
        const float var = ss * (1.f / 512.f) - m * m;   // biased, matches jnp.var
        mu[j] = m;
        rstd[j] = rsqrtf(var + 1e-5f);
    }
}

// Branch 0, kernel C: BN + relu + GEMM2 (512x256x1024). One block per row.
__global__ __launch_bounds__(256) void k_b0_back(
    const float* __restrict__ h, const float* __restrict__ mu,
    const float* __restrict__ rstd, const float* __restrict__ gamma,
    const float* __restrict__ beta, const float* __restrict__ W2,
    const float* __restrict__ b2, float* __restrict__ out0)
{
    __shared__ __align__(16) float hs[1024];
    const int i = blockIdx.x;       // 0..511
    const int tid = threadIdx.x;    // 0..255
    {
        float4 v = ((const float4*)h)[i * 256 + tid];
        const float4 m = ((const float4*)mu)[tid];
        const float4 rs = ((const float4*)rstd)[tid];
        const float4 gm = ((const float4*)gamma)[tid];
        const float4 bt = ((const float4*)beta)[tid];
        float4 o;
        o.x = fmaxf((v.x - m.x) * rs.x * gm.x + bt.x, 0.f);
        o.y = fmaxf((v.y - m.y) * rs.y * gm.y + bt.y, 0.f);
        o.z = fmaxf((v.z - m.z) * rs.z * gm.z + bt.z, 0.f);
        o.w = fmaxf((v.w - m.w) * rs.w * gm.w + bt.w, 0.f);
        ((float4*)hs)[tid] = o;
    }
    __syncthreads();
    const float4* wr = (const float4*)(W2 + (size_t)tid * 1024);
    const float4* hr = (const float4*)hs;
    float acc = 0.f;
    #pragma unroll 4
    for (int k = 0; k < 256; ++k) {
        const float4 wv = wr[k]; const float4 a = hr[k];
        acc += a.x*wv.x + a.y*wv.y + a.z*wv.z + a.w*wv.w;
    }
    out0[(size_t)i * 256 + tid] = acc + b2[tid];
}

// ---------------------------------------------------------------------------
extern "C" void kernel_launch(void* const* d_in, const int* in_sizes, int n_in,
                              void* d_out, int out_size, void* d_ws, size_t ws_size,
                              hipStream_t stream) {
    const float* feat0 = (const float*)d_in[0];
    const float* feat1 = (const float*)d_in[1];
    const float* W1    = (const float*)d_in[2];
    const float* b1    = (const float*)d_in[3];
    const float* gamma = (const float*)d_in[4];
    const float* beta  = (const float*)d_in[5];
    const float* W2    = (const float*)d_in[6];
    const float* b2    = (const float*)d_in[7];
    const float* W3    = (const float*)d_in[8];
    const float* b3    = (const float*)d_in[9];
    const float* W4    = (const float*)d_in[10];
    const float* b4    = (const float*)d_in[11];
    const int* patch_id0 = (const int*)d_in[12];
    const int* patch_id1 = (const int*)d_in[13];
    const int* local_id0 = (const int*)d_in[14];
    const int* local_id1 = (const int*)d_in[15];

    float* out0 = (float*)d_out;                 // (512, 256)
    float* out1 = out0 + 512 * 256;              // (4096, 41, 256)

    float* ws   = (float*)d_ws;
    float* h    = ws;               // 512*1024
    float* mu   = ws + 524288;      // 1024
    float* rstd = ws + 525312;      // 1024

    // dominant kernel first
    k_branch1<<<4096, 256, 0, stream>>>(feat1, patch_id1, local_id1, W3, b3, W4, b4, out1);

    // branch 0 chain (3 kernels)
    k_b0_front<<<512, 256, 0, stream>>>(feat0, patch_id0, local_id0, W1, b1, h);
    k_bnstats<<<1024, 64, 0, stream>>>(h, mu, rstd);
    k_b0_back<<<512, 256, 0, stream>>>(h, mu, rstd, gamma, beta, W2, b2, out0);
}

// Round 3
// 1496.936 us; speedup vs baseline: 5.2094x; 5.2094x over previous
//
#include <hip/hip_runtime.h>
#include <hip/hip_fp16.h>
#include <math.h>

// ---------------------------------------------------------------------------
// Branch 1: fused sample (top-40 of 80 cosine sims) + MLP (64->256 relu ->256)
// + L2 normalize. One block per (b, n) pair; 4096 blocks, 256 threads.
// LDS plan (~35 KB): region A (22.5 KB) = xall[81][65] fp32 gather buffer,
// later reused as t1h[44][256] fp16; region B (11.3 KB) = xs[44][64] fp32.
// NOTE: plain __launch_bounds__(256) — round 2 showed (256,4) caps VGPR at 64
// and spills ~36 GB of scratch traffic. 11x4 reg tile needs ~136 VGPRs.
// ---------------------------------------------------------------------------
__global__ __launch_bounds__(256) void k_branch1(
    const float* __restrict__ feat1, const int* __restrict__ patch_id1,
    const int* __restrict__ local_id1, const float* __restrict__ W3,
    const float* __restrict__ b3, const float* __restrict__ W4,
    const float* __restrict__ b4, float* __restrict__ out1)
{
    __shared__ __align__(16) char regA[44 * 256 * 2];   // 22528 B
    __shared__ __align__(16) float xs[44 * 64];         // 11264 B
    __shared__ double normd[81];
    __shared__ double sims[80];
    __shared__ int winners[40];

    float* xall = (float*)regA;        // [81][65] fp32 (21060 B <= 22528)
    __half* t1h = (__half*)regA;       // [44][256] fp16

    const int row = blockIdx.x;          // 0..4095
    const int b = row >> 9;
    const int n = row & 511;
    const int tid = threadIdx.x;
    const float* fb = feat1 + (size_t)b * 64 * 16384;   // (C=64, HW=16384)
    const int pid = patch_id1[n];
    const int* lids = local_id1 + n * 80;

    // phase 1: gather 81 rows (80 local + center) into LDS
    #pragma unroll 4
    for (int idx = tid; idx < 81 * 64; idx += 256) {
        const int c = idx / 81;
        const int l = idx - c * 81;
        const int pix = (l < 80) ? lids[l] : pid;
        xall[l * 65 + c] = fb[(size_t)c * 16384 + pix];
    }
    __syncthreads();

    // phase 2: row norms (fp64) — t-th thread does row t
    if (tid < 81) {
        double q = 0.0;
        #pragma unroll 8
        for (int c = 0; c < 64; ++c) {
            const double v = (double)xall[tid * 65 + c];
            q += v * v;
        }
        double nl = sqrt(q); if (nl < 1e-12) nl = 1e-12;
        normd[tid] = nl;
    }
    __syncthreads();

    // phase 3: cosine sims vs center (row 80)
    if (tid < 80) {
        double d = 0.0;
        #pragma unroll 8
        for (int c = 0; c < 64; ++c)
            d += (double)xall[tid * 65 + c] * (double)xall[80 * 65 + c];
        sims[tid] = d / (normd[tid] * normd[80]);
    }
    __syncthreads();

    // phase 4: stable top-40 via rank (matches jax.lax.top_k tie-break)
    if (tid < 80) {
        const double s = sims[tid];
        int rank = 0;
        for (int j = 0; j < 80; ++j) {
            const double sj = sims[j];
            rank += (sj > s) || (sj == s && j < tid);
        }
        if (rank < 40) winners[rank] = tid;
    }
    __syncthreads();

    // phase 5: build xs (row 0 = center, 1..40 winners, 41..43 pad) from LDS
    for (int m = tid; m < 44 * 64; m += 256) {
        const int mi = m >> 6, c = m & 63;
        const int src = (mi >= 1 && mi <= 40) ? winners[mi - 1] : 80;
        xs[m] = xall[src * 65 + c];
    }
    __syncthreads();   // after this, xall region is dead -> t1h may overwrite

    const int jg = tid & 63;   // column group (4 consecutive cols)
    const int g = tid >> 6;    // mi-group (one wave each)
    const int j0 = jg * 4;
    const int mb = g * 11;

    // ---- stage 1: t1 = relu(xs @ W3^T + b3) -> t1h (fp16) ----
    {
        float acc[11][4];
        #pragma unroll
        for (int r = 0; r < 11; ++r) {
            acc[r][0] = 0.f; acc[r][1] = 0.f; acc[r][2] = 0.f; acc[r][3] = 0.f;
        }
        const float4* W3f = (const float4*)W3;   // row j: W3f[j*16 + c4]
        const float4* xsf = (const float4*)xs;   // row mi: xsf[mi*16 + c4]
        #pragma unroll 4
        for (int c4 = 0; c4 < 16; ++c4) {
            const float4 w0 = W3f[(j0 + 0) * 16 + c4];
            const float4 w1 = W3f[(j0 + 1) * 16 + c4];
            const float4 w2 = W3f[(j0 + 2) * 16 + c4];
            const float4 w3 = W3f[(j0 + 3) * 16 + c4];
            #pragma unroll
            for (int r = 0; r < 11; ++r) {
                const float4 x4 = xsf[(mb + r) * 16 + c4];  // LDS broadcast
                acc[r][0] += x4.x*w0.x + x4.y*w0.y + x4.z*w0.z + x4.w*w0.w;
                acc[r][1] += x4.x*w1.x + x4.y*w1.y + x4.z*w1.z + x4.w*w1.w;
                acc[r][2] += x4.x*w2.x + x4.y*w2.y + x4.z*w2.z + x4.w*w2.w;
                acc[r][3] += x4.x*w3.x + x4.y*w3.y + x4.z*w3.z + x4.w*w3.w;
            }
        }
        const float bb0 = b3[j0], bb1 = b3[j0+1], bb2 = b3[j0+2], bb3 = b3[j0+3];
        #pragma unroll
        for (int r = 0; r < 11; ++r) {
            const float v0 = fmaxf(acc[r][0] + bb0, 0.f);
            const float v1 = fmaxf(acc[r][1] + bb1, 0.f);
            const float v2 = fmaxf(acc[r][2] + bb2, 0.f);
            const float v3 = fmaxf(acc[r][3] + bb3, 0.f);
            union { __half2 h2[2]; float2 f2; } u;
            u.h2[0] = __floats2half2_rn(v0, v1);
            u.h2[1] = __floats2half2_rn(v2, v3);
            *(float2*)&t1h[(mb + r) * 256 + j0] = u.f2;   // 8B store
        }
    }
    __syncthreads();

    // ---- stage 2: y = t1 @ W4^T + b4, L2-normalize, store ----
    {
        float acc[11][4];
        #pragma unroll
        for (int r = 0; r < 11; ++r) {
            acc[r][0] = 0.f; acc[r][1] = 0.f; acc[r][2] = 0.f; acc[r][3] = 0.f;
        }
        const float4* W4f = (const float4*)W4;    // row j: W4f[j*64 + k4]
        const float4* t1f = (const float4*)t1h;   // row mi: t1f[mi*32 + j8] (8 halves)
        #pragma unroll 2
        for (int j8 = 0; j8 < 32; ++j8) {
            const float4 w00 = W4f[(j0 + 0) * 64 + j8 * 2 + 0];
            const float4 w01 = W4f[(j0 + 0) * 64 + j8 * 2 + 1];
            const float4 w10 = W4f[(j0 + 1) * 64 + j8 * 2 + 0];
            const float4 w11 = W4f[(j0 + 1) * 64 + j8 * 2 + 1];
            const float4 w20 = W4f[(j0 + 2) * 64 + j8 * 2 + 0];
            const float4 w21 = W4f[(j0 + 2) * 64 + j8 * 2 + 1];
            const float4 w30 = W4f[(j0 + 3) * 64 + j8 * 2 + 0];
            const float4 w31 = W4f[(j0 + 3) * 64 + j8 * 2 + 1];
            #pragma unroll
            for (int r = 0; r < 11; ++r) {
                const float4 tv = t1f[(mb + r) * 32 + j8];  // LDS broadcast, 8 halves
                const __half2* hp = (const __half2*)&tv;
                const float2 a0 = __half22float2(hp[0]);
                const float2 a1 = __half22float2(hp[1]);
                const float2 a2 = __half22float2(hp[2]);
                const float2 a3 = __half22float2(hp[3]);
                acc[r][0] += a0.x*w00.x + a0.y*w00.y + a1.x*w00.z + a1.y*w00.w
                           + a2.x*w01.x + a2.y*w01.y + a3.x*w01.z + a3.y*w01.w;
                acc[r][1] += a0.x*w10.x + a0.y*w10.y + a1.x*w10.z + a1.y*w10.w
                           + a2.x*w11.x + a2.y*w11.y + a3.x*w11.z + a3.y*w11.w;
                acc[r][2] += a0.x*w20.x + a0.y*w20.y + a1.x*w20.z + a1.y*w20.w
                           + a2.x*w21.x + a2.y*w21.y + a3.x*w21.z + a3.y*w21.w;
                acc[r][3] += a0.x*w30.x + a0.y*w30.y + a1.x*w30.z + a1.y*w30.w
                           + a2.x*w31.x + a2.y*w31.y + a3.x*w31.z + a3.y*w31.w;
            }
        }
        const float bb0 = b4[j0], bb1 = b4[j0+1], bb2 = b4[j0+2], bb3 = b4[j0+3];
        #pragma unroll
        for (int r = 0; r < 11; ++r) {
            const float y0 = acc[r][0] + bb0;
            const float y1 = acc[r][1] + bb1;
            const float y2 = acc[r][2] + bb2;
            const float y3 = acc[r][3] + bb3;
            float p = y0*y0 + y1*y1 + y2*y2 + y3*y3;
            for (int o = 1; o < 64; o <<= 1) p += __shfl_xor(p, o);
            const float inv = 1.f / (sqrtf(p) + 1e-7f);
            const int mi = mb + r;
            if (mi < 41) {
                float4 o4 = make_float4(y0*inv, y1*inv, y2*inv, y3*inv);
                *(float4*)&out1[((size_t)row * 41 + mi) * 256 + j0] = o4;
            }
        }
    }
}

// ---------------------------------------------------------------------------
// Branch 0, kernel A: sample + mean + GEMM1 (512x1024x512). One block per row.
// ---------------------------------------------------------------------------
__global__ __launch_bounds__(256) void k_b0_front(
    const float* __restrict__ feat0, const int* __restrict__ patch_id0,
    const int* __restrict__ local_id0, const float* __restrict__ W1,
    const float* __restrict__ b1, float* __restrict__ h)
{
    __shared__ __align__(16) float loc[9][512];   // rows 0..7 local, 8 = center
    __shared__ __align__(16) float xm[512];
    __shared__ double normd[9];
    __shared__ double sims[8];
    __shared__ int winners[4];

    const int row = blockIdx.x;          // 0..511
    const int b = row >> 6;
    const int n = row & 63;
    const int tid = threadIdx.x;
    const int lane = tid & 63;
    const int w = tid >> 6;
    const float* fb = feat0 + (size_t)b * 512 * 64;   // (C=512, HW=64)
    const int pid = patch_id0[n];

    for (int idx = tid; idx < 9 * 512; idx += 256) {
        const int l = idx >> 9, c = idx & 511;
        const int pix = (l < 8) ? local_id0[n * 8 + l] : pid;
        loc[l][c] = fb[(size_t)c * 64 + pix];
    }
    __syncthreads();

    // norms (fp64), wave w handles rows w, w+4, ...
    for (int l = w; l < 9; l += 4) {
        double q = 0.0;
        for (int c = lane; c < 512; c += 64) {
            const double v = (double)loc[l][c];
            q += v * v;
        }
        for (int o = 32; o > 0; o >>= 1) q += __shfl_down(q, o);
        if (lane == 0) {
            double nl = sqrt(q); if (nl < 1e-12) nl = 1e-12;
            normd[l] = nl;
        }
    }
    __syncthreads();

    for (int l = w; l < 8; l += 4) {
        double d = 0.0;
        for (int c = lane; c < 512; c += 64)
            d += (double)loc[l][c] * (double)loc[8][c];
        for (int o = 32; o > 0; o >>= 1) d += __shfl_down(d, o);
        if (lane == 0) sims[l] = d / (normd[l] * normd[8]);
    }
    __syncthreads();

    if (tid < 8) {
        const double s = sims[tid];
        int rank = 0;
        for (int j = 0; j < 8; ++j) {
            const double sj = sims[j];
            rank += (sj > s) || (sj == s && j < tid);
        }
        if (rank < 4) winners[rank] = tid;
    }
    __syncthreads();

    for (int c = tid; c < 512; c += 256) {
        float a = loc[8][c];
        for (int r = 0; r < 4; ++r) a += loc[winners[r]][c];
        xm[c] = a * 0.2f;
    }
    __syncthreads();

    // GEMM1: thread computes cols j0..j0+3 of h row
    {
        const int j0 = tid * 4;
        float a0 = 0.f, a1 = 0.f, a2 = 0.f, a3 = 0.f;
        const float4* W1f = (const float4*)W1;   // row j: W1f[j*128 + k]
        const float4* xf = (const float4*)xm;
        #pragma unroll 4
        for (int k = 0; k < 128; ++k) {
            const float4 x4 = xf[k];
            const float4 w0 = W1f[(j0 + 0) * 128 + k];
            const float4 w1 = W1f[(j0 + 1) * 128 + k];
            const float4 w2 = W1f[(j0 + 2) * 128 + k];
            const float4 w3 = W1f[(j0 + 3) * 128 + k];
            a0 += x4.x*w0.x + x4.y*w0.y + x4.z*w0.z + x4.w*w0.w;
            a1 += x4.x*w1.x + x4.y*w1.y + x4.z*w1.z + x4.w*w1.w;
            a2 += x4.x*w2.x + x4.y*w2.y + x4.z*w2.z + x4.w*w2.w;
            a3 += x4.x*w3.x + x4.y*w3.y + x4.z*w3.z + x4.w*w3.w;
        }
        float4 o4 = make_float4(a0 + b1[j0], a1 + b1[j0+1], a2 + b1[j0+2], a3 + b1[j0+3]);
        *(float4*)&h[(size_t)row * 1024 + j0] = o4;
    }
}

__global__ __launch_bounds__(64) void k_bnstats(
    const float* __restrict__ h, float* __restrict__ mu, float* __restrict__ rstd)
{
    const int j = blockIdx.x;   // 0..1023
    const int t = threadIdx.x;  // 64
    float s = 0.f, ss = 0.f;
    for (int i = t; i < 512; i += 64) {
        const float v = h[(size_t)i * 1024 + j];
        s += v; ss += v * v;
    }
    for (int o = 32; o > 0; o >>= 1) { s += __shfl_down(s, o); ss += __shfl_down(ss, o); }
    if (t == 0) {
        const float m = s * (1.f / 512.f);
        const float var = ss * (1.f / 512.f) - m * m;   // biased, matches jnp.var
        mu[j] = m;
        rstd[j] = rsqrtf(var + 1e-5f);
    }
}

// Branch 0, kernel C: BN + relu + GEMM2 (512x256x1024). One block per row.
__global__ __launch_bounds__(256) void k_b0_back(
    const float* __restrict__ h, const float* __restrict__ mu,
    const float* __restrict__ rstd, const float* __restrict__ gamma,
    const float* __restrict__ beta, const float* __restrict__ W2,
    const float* __restrict__ b2, float* __restrict__ out0)
{
    __shared__ __align__(16) float hs[1024];
    const int i = blockIdx.x;       // 0..511
    const int tid = threadIdx.x;    // 0..255
    {
        float4 v = ((const float4*)h)[i * 256 + tid];
        const float4 m = ((const float4*)mu)[tid];
        const float4 rs = ((const float4*)rstd)[tid];
        const float4 gm = ((const float4*)gamma)[tid];
        const float4 bt = ((const float4*)beta)[tid];
        float4 o;
        o.x = fmaxf((v.x - m.x) * rs.x * gm.x + bt.x, 0.f);
        o.y = fmaxf((v.y - m.y) * rs.y * gm.y + bt.y, 0.f);
        o.z = fmaxf((v.z - m.z) * rs.z * gm.z + bt.z, 0.f);
        o.w = fmaxf((v.w - m.w) * rs.w * gm.w + bt.w, 0.f);
        ((float4*)hs)[tid] = o;
    }
    __syncthreads();
    const float4* wr = (const float4*)(W2 + (size_t)tid * 1024);
    const float4* hr = (const float4*)hs;
    float acc = 0.f;
    #pragma unroll 4
    for (int k = 0; k < 256; ++k) {
        const float4 wv = wr[k]; const float4 a = hr[k];
        acc += a.x*wv.x + a.y*wv.y + a.z*wv.z + a.w*wv.w;
    }
    out0[(size_t)i * 256 + tid] = acc + b2[tid];
}

// ---------------------------------------------------------------------------
extern "C" void kernel_launch(void* const* d_in, const int* in_sizes, int n_in,
                              void* d_out, int out_size, void* d_ws, size_t ws_size,
                              hipStream_t stream) {
    const float* feat0 = (const float*)d_in[0];
    const float* feat1 = (const float*)d_in[1];
    const float* W1    = (const float*)d_in[2];
    const float* b1    = (const float*)d_in[3];
    const float* gamma = (const float*)d_in[4];
    const float* beta  = (const float*)d_in[5];
    const float* W2    = (const float*)d_in[6];
    const float* b2    = (const float*)d_in[7];
    const float* W3    = (const float*)d_in[8];
    const float* b3    = (const float*)d_in[9];
    const float* W4    = (const float*)d_in[10];
    const float* b4    = (const float*)d_in[11];
    const int* patch_id0 = (const int*)d_in[12];
    const int* patch_id1 = (const int*)d_in[13];
    const int* local_id0 = (const int*)d_in[14];
    const int* local_id1 = (const int*)d_in[15];

    float* out0 = (float*)d_out;                 // (512, 256)
    float* out1 = out0 + 512 * 256;              // (4096, 41, 256)

    float* ws   = (float*)d_ws;
    float* h    = ws;               // 512*1024
    float* mu   = ws + 524288;      // 1024
    float* rstd = ws + 525312;      // 1024

    // dominant kernel first
    k_branch1<<<4096, 256, 0, stream>>>(feat1, patch_id1, local_id1, W3, b3, W4, b4, out1);

    // branch 0 chain (3 kernels)
    k_b0_front<<<512, 256, 0, stream>>>(feat0, patch_id0, local_id0, W1, b1, h);
    k_bnstats<<<1024, 64, 0, stream>>>(h, mu, rstd);
    k_b0_back<<<512, 256, 0, stream>>>(h, mu, rstd, gamma, beta, W2, b2, out0);
}